// Round 7
// baseline (548.075 us; speedup 1.0000x reference)
//
#include <hip/hip_runtime.h>

// SPRTFlipLinear: y = x @ W^T, W = ternary * per-128-group scales.
// M=8192, N=4096, K=4096. 274.9 GFLOP/call.
// R10: revert R9 merge (regressed 239->272: coarse granules serialize pipes).
//     R8 structure + REGISTER DOUBLE-BUFFERED FRAGMENTS: phase k MFMAs on
//     frags loaded in k-1 while issuing ds_reads for k+1 -> LDS-read pipe
//     (~2300cy/K-tile) overlaps MFMA pipe (~2066cy) instead of serializing
//     (R8 wall 4482cy ~= their sum). VMBARs move P4/P8-end -> P3/P7-end
//     vmcnt(4) so P4/P8 prefetches are RAW-safe. Frag regs: afA/afB[2][4],
//     bfrA/bfrB[4] (+32 VGPR). Per-acc MFMA order unchanged (k4 ascending
//     per tile) -> bitwise-identical output. prep: unchanged R0 one-shot.

#define IN_F  4096
#define OUT_F 4096
#define MROWS 8192
#define GROUP 128

#define BM 256
#define BN 256
#define BK 64
#define NKT   (IN_F / BK)   // 64 K-tiles
#define NITER (NKT / 2)     // 32 double-tile iterations

#define CVT_BLOCKS ((MROWS * IN_F) / 8 / 256)   // 16384
#define DQ_BLOCKS  ((OUT_F * IN_F) / 8 / 256)   // 8192

using bf16x8 = __attribute__((ext_vector_type(8))) __bf16;
using f32x16 = __attribute__((ext_vector_type(16))) float;

#define GLOBAL_AS __attribute__((address_space(1)))
#define LDS_AS    __attribute__((address_space(3)))

__device__ __forceinline__ unsigned short f2bf(float f) {
  unsigned int u = __float_as_uint(f);
  u += 0x7fffu + ((u >> 16) & 1u);
  return (unsigned short)(u >> 16);
}

// One-shot prep (R0 pattern): blocks [0, CVT_BLOCKS) convert x f32->bf16
// (8 elems/lane); rest dequant ternary->bf16.
__global__ void prep_kernel(const float* __restrict__ x, unsigned short* __restrict__ xb,
                            const int* __restrict__ t, const float* __restrict__ s,
                            unsigned short* __restrict__ wb) {
  int b = blockIdx.x;
  if (b < CVT_BLOCKS) {
    const int i = (b * 256 + (int)threadIdx.x) * 8;
    const float4 a0 = *(const float4*)(x + i);
    const float4 a1 = *(const float4*)(x + i + 4);
    union { unsigned short u[8]; uint4 v; } o;
    o.u[0] = f2bf(a0.x); o.u[1] = f2bf(a0.y); o.u[2] = f2bf(a0.z); o.u[3] = f2bf(a0.w);
    o.u[4] = f2bf(a1.x); o.u[5] = f2bf(a1.y); o.u[6] = f2bf(a1.z); o.u[7] = f2bf(a1.w);
    *(uint4*)(xb + i) = o.v;
  } else {
    const int i = ((b - CVT_BLOCKS) * 256 + (int)threadIdx.x) * 8;
    const float sc = s[i >> 7];  // GROUP=128
    const int4 t0 = *(const int4*)(t + i);
    const int4 t1 = *(const int4*)(t + i + 4);
    union { unsigned short u[8]; uint4 v; } o;
    o.u[0] = f2bf((float)t0.x * sc); o.u[1] = f2bf((float)t0.y * sc);
    o.u[2] = f2bf((float)t0.z * sc); o.u[3] = f2bf((float)t0.w * sc);
    o.u[4] = f2bf((float)t1.x * sc); o.u[5] = f2bf((float)t1.y * sc);
    o.u[6] = f2bf((float)t1.z * sc); o.u[7] = f2bf((float)t1.w * sc);
    *(uint4*)(wb + i) = o.v;
  }
}

// ---------------- 256x256 8-phase GEMM, reg-dbuf fragments ----------------
// 512 threads = 8 waves (2M x 4N), wave tile 128x64 = quadrants Q(qm,qn) of
// 64x32 (2 sm-frags x 1 nfrag of 32x32x16, 4 ksteps).
// Phase k: [stages] [prefetch frags for phase k+1] sched_barrier
//          [MFMA8 on frags from phase k-1] [BAR or VMBAR].
// Frag schedule: P8'->afA,bfrA(t,h0); P1->bfrB(t,h1); P2->afB(t,h1);
//   P4->afA,bfrA(u,h0); P5->bfrB(u,h1); P6->afB(u,h1); P8->afA,bfrA(t2,h0).
// MFMA: P1:Q(0,0)afA,bfrA  P2:Q(0,1)afA,bfrB  P3:Q(1,0)afB,bfrA
//       P4:Q(1,1)afB,bfrB  P5-P8 same on tile u.
//
// vmcnt ledger (2 loads/stage; stages P1:u.A1 P2:t2.A0 P3:t2.B0 P4:t2.B1
// P5:t2.A1 P6:t3.A0 P7:t3.B0 P8:t3.B1): iter entry 6 in flight (u.A0,B0,B1).
// P3-end: 6+P1+P2+P3=12, VMBAR(4) drains 8 oldest = ALL of u (before P4
// prefetches buf1) leaving t2.A0,B0. P7-end: 4+P4+P5+P6+P7=12, VMBAR(4)
// drains 8 = ALL of t2 (before P8 prefetches buf0) leaving t3.A0,B0. P8
// stages t3.B1 -> 6 at next iter entry. Prologue: 14 issued, VMBAR(6) =
// tile0 landed, 6 left. Last iter: P3-end VMBAR(0) (8->0); P7/P8 plain BAR.
//
// WAR audit (read complete @ lgkm before consuming MFMA -> stage phase):
//  buf0.A.h0 rd<=P1, staged P2 | buf0.B.h0 rd<=P1(reg-reused Q3), staged P3
//  buf0.B.h1 rd<=P2, staged P4 | buf0.A.h1 rd<=P3, staged P5
//  buf1.A.h0 rd<=P5, staged P6 | buf1.B.h0 rd<=P5, staged P7
//  buf1.B.h1 rd<=P6, staged P8 | buf1.A.h1 rd<=P7, staged next-P1.  All >=1 bar.

#define FENCE asm volatile("" ::: "memory")
#define BAR() do { FENCE; __builtin_amdgcn_s_barrier(); FENCE; } while (0)
#define VMBAR(N) do { asm volatile("s_waitcnt vmcnt(" #N ")" ::: "memory"); \
                      __builtin_amdgcn_s_barrier(); FENCE; } while (0)
#define SB0 __builtin_amdgcn_sched_barrier(0)

__global__ __launch_bounds__(512, 2) void gemm_bt_kernel(const unsigned short* __restrict__ A,
                                                         const unsigned short* __restrict__ B,
                                                         float* __restrict__ C) {
  __shared__ unsigned short lds[65536];  // 128 KiB

  const int tid  = threadIdx.x;
  const int lane = tid & 63;
  const int wv   = tid >> 6;      // 0..7
  const int wm   = wv & 1;        // M pair (rows wm*64 and 128+wm*64)
  const int wn   = wv >> 1;       // N quad (cols wn*32 and 128+wn*32)
  const int r32  = lane & 31;
  const int kh   = lane >> 5;     // k-half of fragment

  // bijective XCD chunk swizzle: 512 blocks -> 8 XCDs x (8 rows x 8 cols) chunks
  const int bid = blockIdx.x;
  const int xcd = bid & 7;
  const int loc = bid >> 3;                    // 0..63
  const int by  = (xcd >> 1) * 8 + (loc >> 3); // 0..31
  const int bx  = (xcd & 1) * 8 + (loc & 7);   // 0..15
  const int m0  = by * BM;
  const int n0  = bx * BN;

  // ---- staging geometry: instruction i covers chunk = wv*2+i (8 rows x 8 slots);
  // lane slot (srow = lane>>3, lane&7); source k-chunk = (lane&7) ^ srow ^ (chunk&7).
  const int srow = lane >> 3;
  const int l7   = lane & 7;
  const int rowoff0 = (wv * 2 + 0) * 8 + srow;
  const int rowoff1 = (wv * 2 + 1) * 8 + srow;
  const int sc0 = (l7 ^ srow ^ ((wv * 2 + 0) & 7)) * 8;
  const int sc1 = (l7 ^ srow ^ ((wv * 2 + 1) & 7)) * 8;
  const unsigned short* pA0 = A + (size_t)(m0 + rowoff0) * IN_F + sc0;
  const unsigned short* pA1 = A + (size_t)(m0 + rowoff1) * IN_F + sc1;
  const unsigned short* pB0 = B + (size_t)(n0 + rowoff0) * IN_F + sc0;
  const unsigned short* pB1 = B + (size_t)(n0 + rowoff1) * IN_F + sc1;

#define STAGE_A(bufi, h, kcol) do { \
    __builtin_amdgcn_global_load_lds((const GLOBAL_AS unsigned int*)(pA0 + (size_t)(h) * 128 * IN_F + (kcol)), \
        (LDS_AS unsigned int*)((char*)lds + (bufi) * 32768 + (h) * 16384 + (wv * 2 + 0) * 1024), 16, 0, 0); \
    __builtin_amdgcn_global_load_lds((const GLOBAL_AS unsigned int*)(pA1 + (size_t)(h) * 128 * IN_F + (kcol)), \
        (LDS_AS unsigned int*)((char*)lds + (bufi) * 32768 + (h) * 16384 + (wv * 2 + 1) * 1024), 16, 0, 0); \
  } while (0)

#define STAGE_B(bufi, h, kcol) do { \
    __builtin_amdgcn_global_load_lds((const GLOBAL_AS unsigned int*)(pB0 + (size_t)(h) * 128 * IN_F + (kcol)), \
        (LDS_AS unsigned int*)((char*)lds + 65536 + (bufi) * 32768 + (h) * 16384 + (wv * 2 + 0) * 1024), 16, 0, 0); \
    __builtin_amdgcn_global_load_lds((const GLOBAL_AS unsigned int*)(pB1 + (size_t)(h) * 128 * IN_F + (kcol)), \
        (LDS_AS unsigned int*)((char*)lds + 65536 + (bufi) * 32768 + (h) * 16384 + (wv * 2 + 1) * 1024), 16, 0, 0); \
  } while (0)

  // ---- read geometry: precomputed byte offsets (buf/half added as imm at the read)
  const int rA = wm * 64 + r32;   // A row-in-half for sm=0 (sm adds 32)
  const int rB = wn * 32 + r32;   // B row-in-half
  int offA[2][4];
  int offB[4];
#pragma unroll
  for (int sm = 0; sm < 2; ++sm) {
    const int fh = ((sm * 4) + (r32 >> 3)) & 7;   // ((row>>3)&7); wm*8 drops mod 8
#pragma unroll
    for (int k4 = 0; k4 < 4; ++k4) {
      const int pc = (2 * k4 + kh) ^ (r32 & 7) ^ fh;
      offA[sm][k4] = (rA + sm * 32) * 128 + pc * 16;
    }
  }
  {
    const int fh = ((wn * 4) + (r32 >> 3)) & 7;
#pragma unroll
    for (int k4 = 0; k4 < 4; ++k4) {
      const int pc = (2 * k4 + kh) ^ (r32 & 7) ^ fh;
      offB[k4] = 65536 + rB * 128 + pc * 16;
    }
  }

  bf16x8 afA[2][4], afB[2][4], bfrA[4], bfrB[4];

#define LOAD_AF(AF, bufi, h) do { \
    _Pragma("unroll") for (int sm = 0; sm < 2; ++sm) \
    _Pragma("unroll") for (int k4 = 0; k4 < 4; ++k4) \
      AF[sm][k4] = *(const bf16x8*)((const char*)lds + offA[sm][k4] + (bufi) * 32768 + (h) * 16384); \
  } while (0)

#define LOAD_BF(BF, bufi, h) do { \
    _Pragma("unroll") for (int k4 = 0; k4 < 4; ++k4) \
      BF[k4] = *(const bf16x8*)((const char*)lds + offB[k4] + (bufi) * 32768 + (h) * 16384); \
  } while (0)

// 8 MFMAs for quadrant (qm,qn); k4 outer (dep distance 2). Per-acc k4 order
// ascending -> same numerics as R8.
#define MFMA8(qm, qn, AF, BF) do { \
    __builtin_amdgcn_s_setprio(1); \
    _Pragma("unroll") for (int k4 = 0; k4 < 4; ++k4) \
    _Pragma("unroll") for (int sm = 0; sm < 2; ++sm) \
      acc[qm][sm][qn] = __builtin_amdgcn_mfma_f32_32x32x16_bf16(AF[sm][k4], BF[k4], acc[qm][sm][qn], 0, 0, 0); \
    __builtin_amdgcn_s_setprio(0); \
  } while (0)

  f32x16 acc[2][2][2];
#pragma unroll
  for (int a = 0; a < 2; ++a)
#pragma unroll
    for (int b = 0; b < 2; ++b)
#pragma unroll
      for (int c = 0; c < 2; ++c)
        acc[a][b][c] = (f32x16)(0.0f);

  // ---- prologue: tile0 -> buf0, tile1 A0/B0/B1 -> buf1 (14 loads);
  // wait tile0; preload Q1 fragments.
  STAGE_A(0, 0, 0); STAGE_B(0, 0, 0); STAGE_B(0, 1, 0); STAGE_A(0, 1, 0);
  STAGE_A(1, 0, BK); STAGE_B(1, 0, BK); STAGE_B(1, 1, BK);
  VMBAR(6);  // tile0 fully landed; tile1 A0/B0/B1 in flight
  LOAD_AF(afA, 0, 0); LOAD_BF(bfrA, 0, 0);

#pragma unroll 1
  for (int j = 0; j < NITER; ++j) {
    const int ku = (2 * j + 1) * BK;
    const int k2 = (2 * j + 2) * BK;
    const int k3 = (2 * j + 3) * BK;
    const bool more = (j < NITER - 1);

    // P1: MFMA Q(t,0,0); stage u.A1; prefetch bfrB <- B(t,h1)
    STAGE_A(1, 1, ku);
    LOAD_BF(bfrB, 0, 1);
    SB0; MFMA8(0, 0, afA, bfrA);
    BAR();

    // P2: MFMA Q(t,0,1); stage t2.A0; prefetch afB <- A(t,h1)
    if (more) STAGE_A(0, 0, k2);
    LOAD_AF(afB, 0, 1);
    SB0; MFMA8(0, 1, afA, bfrB);
    BAR();

    // P3: MFMA Q(t,1,0); stage t2.B0; end: wait ALL of u landed
    if (more) STAGE_B(0, 0, k2);
    SB0; MFMA8(1, 0, afB, bfrA);
    if (more) { VMBAR(4); } else { VMBAR(0); }

    // P4: MFMA Q(t,1,1); stage t2.B1; prefetch afA,bfrA <- A/B(u,h0)
    if (more) STAGE_B(0, 1, k2);
    LOAD_AF(afA, 1, 0); LOAD_BF(bfrA, 1, 0);
    SB0; MFMA8(1, 1, afB, bfrB);
    BAR();

    // P5: MFMA Q(u,0,0); stage t2.A1; prefetch bfrB <- B(u,h1)
    if (more) STAGE_A(0, 1, k2);
    LOAD_BF(bfrB, 1, 1);
    SB0; MFMA8(0, 0, afA, bfrA);
    BAR();

    // P6: MFMA Q(u,0,1); stage t3.A0; prefetch afB <- A(u,h1)
    if (more) STAGE_A(1, 0, k3);
    LOAD_AF(afB, 1, 1);
    SB0; MFMA8(0, 1, afA, bfrB);
    BAR();

    // P7: MFMA Q(u,1,0); stage t3.B0; end: wait ALL of t2 landed
    if (more) STAGE_B(1, 0, k3);
    SB0; MFMA8(1, 0, afB, bfrA);
    if (more) { VMBAR(4); } else { BAR(); }

    // P8: MFMA Q(u,1,1); stage t3.B1; prefetch afA,bfrA <- A/B(t2,h0)
    if (more) {
      STAGE_B(1, 1, k3);
      LOAD_AF(afA, 0, 0); LOAD_BF(bfrA, 0, 0);
    }
    SB0; MFMA8(1, 1, afB, bfrB);
    BAR();
  }

  // ---- epilogue: C/D layout col = lane&31, row = (reg&3)+8*(reg>>2)+4*(lane>>5)
#pragma unroll
  for (int qm = 0; qm < 2; ++qm)
#pragma unroll
    for (int sm = 0; sm < 2; ++sm)
#pragma unroll
      for (int qn = 0; qn < 2; ++qn) {
        const int ncol = n0 + qn * 128 + wn * 32 + r32;
        const int mb   = m0 + qm * 128 + wm * 64 + sm * 32 + 4 * kh;
#pragma unroll
        for (int r = 0; r < 16; ++r) {
          const int mrow = mb + (r & 3) + 8 * (r >> 2);
          C[(size_t)mrow * OUT_F + ncol] = acc[qm][sm][qn][r];
        }
      }
}

extern "C" void kernel_launch(void* const* d_in, const int* in_sizes, int n_in,
                              void* d_out, int out_size, void* d_ws, size_t ws_size,
                              hipStream_t stream) {
  const float* x       = (const float*)d_in[0];   // [4,2048,4096] f32
  const int*   ternary = (const int*)d_in[1];     // [4096,4096] int {-1,0,1}
  const float* scales  = (const float*)d_in[2];   // [131072] f32
  float* out = (float*)d_out;                     // [4,2048,4096] f32

  unsigned short* xb = (unsigned short*)d_ws;                 // 67.1 MB
  unsigned short* wb = xb + (size_t)MROWS * IN_F;             // +33.6 MB

  prep_kernel<<<CVT_BLOCKS + DQ_BLOCKS, 256, 0, stream>>>(x, xb, ternary, scales, wb);

  gemm_bt_kernel<<<(MROWS / BM) * (OUT_F / BN), 512, 0, stream>>>(xb, wb, out);
}

// Round 10
// 498.051 us; speedup vs baseline: 1.1004x; 1.1004x over previous
//
#include <hip/hip_runtime.h>

// SPRTFlipLinear: y = x @ W^T, W = ternary * per-128-group scales.
// M=8192, N=4096, K=4096. 274.9 GFLOP/call.
// R13: R11/R12 died twice at container level with the only never-passed
//      construct being the bf16x8 ext-vector GLOBAL store in prep.
//      De-risk: keep (__bf16)-cast conversion (the VALU lever — compiler
//      emits v_cvt_pk_bf16_f32; RNE == f2bf bitwise, proven in R6) but
//      store via the R8-proven union{u16[8];uint4} -> uint4 global store.
//      GEMM: byte-identical to the R8-verified 8-phase/1-barrier kernel
//      (239us, MfmaUtil 54%, 0 bank conflicts).

#define IN_F  4096
#define OUT_F 4096
#define MROWS 8192
#define GROUP 128

#define BM 256
#define BN 256
#define BK 64
#define NKT   (IN_F / BK)   // 64 K-tiles
#define NITER (NKT / 2)     // 32 double-tile iterations

#define CVT_BLOCKS ((MROWS * IN_F) / 8 / 256)   // 16384
#define DQ_BLOCKS  ((OUT_F * IN_F) / 8 / 256)   // 8192

using bf16x8 = __attribute__((ext_vector_type(8))) __bf16;
using f32x16 = __attribute__((ext_vector_type(16))) float;

#define GLOBAL_AS __attribute__((address_space(1)))
#define LDS_AS    __attribute__((address_space(3)))

__device__ __forceinline__ unsigned short bfbits(float f) {
  __bf16 h = (__bf16)f;                       // RNE fptrunc (v_cvt_pk_bf16_f32 when paired)
  return *(unsigned short*)&h;
}

// One-shot prep (R0 geometry, cast-based convert, uint4 store):
// blocks [0, CVT_BLOCKS) convert x f32->bf16 (8 elems/lane); rest dequant
// ternary->bf16.
__global__ void prep_kernel(const float* __restrict__ x, unsigned short* __restrict__ xb,
                            const int* __restrict__ t, const float* __restrict__ s,
                            unsigned short* __restrict__ wb) {
  int b = blockIdx.x;
  if (b < CVT_BLOCKS) {
    const int i = (b * 256 + (int)threadIdx.x) * 8;
    const float4 a0 = *(const float4*)(x + i);
    const float4 a1 = *(const float4*)(x + i + 4);
    union { unsigned short u[8]; uint4 v; } o;
    o.u[0] = bfbits(a0.x); o.u[1] = bfbits(a0.y); o.u[2] = bfbits(a0.z); o.u[3] = bfbits(a0.w);
    o.u[4] = bfbits(a1.x); o.u[5] = bfbits(a1.y); o.u[6] = bfbits(a1.z); o.u[7] = bfbits(a1.w);
    *(uint4*)(xb + i) = o.v;
  } else {
    const int i = ((b - CVT_BLOCKS) * 256 + (int)threadIdx.x) * 8;
    const float sc = s[i >> 7];  // GROUP=128
    const int4 t0 = *(const int4*)(t + i);
    const int4 t1 = *(const int4*)(t + i + 4);
    union { unsigned short u[8]; uint4 v; } o;
    o.u[0] = bfbits((float)t0.x * sc); o.u[1] = bfbits((float)t0.y * sc);
    o.u[2] = bfbits((float)t0.z * sc); o.u[3] = bfbits((float)t0.w * sc);
    o.u[4] = bfbits((float)t1.x * sc); o.u[5] = bfbits((float)t1.y * sc);
    o.u[6] = bfbits((float)t1.z * sc); o.u[7] = bfbits((float)t1.w * sc);
    *(uint4*)(wb + i) = o.v;
  }
}

// ---------------- 256x256 8-phase GEMM (R8-verified, unchanged) ----------------
// C[M][N] = A[M][K]*B[N][K]^T, bf16 in fp32 out. 512 threads = 8 waves (2M x 4N),
// wave tile 128x64 as 4 quadrants of 64x32 (2 Mfrags x 1 Nfrag of 32x32x16, 4 ksteps).
//
// LDS byte map (131072 B): A: buf*32768 + half*16384 ; B: 65536 + buf*32768 + half*16384.
// Within a half: row r (0..127) at r*128; 16B slot s of row r holds global k-chunk
// s ^ (r&7) ^ ((r>>3)&7)  (involution; realized by permuting the per-lane GLOBAL source,
// gload_lds dest stays linear = base + lane*16).
//
// vmcnt ledger (per wave, 2 loads per stage): steady state at P4/P8 there are 14
// outstanding; vmcnt(6) drains the 8 oldest = exactly one full K-tile, leaving 3
// half-tiles (6 loads) in flight. Prologue: 14 outstanding -> vmcnt(6) = tile0 landed.
// Final iter: P4 VMBAR(0) drains tile63 fully before buf1 reads; P8 plain BAR.
//
// ONE barrier per phase (end-phase). WAR audit: every stage-overwrite is >=1
// end-phase barrier after its region's last read (A0:P1->P2, B0:P1->P3,
// B1:P2->P4, A1:P3->P5; buf1 symmetric; A1:P7->next P1).

#define FENCE asm volatile("" ::: "memory")
#define BAR() do { FENCE; __builtin_amdgcn_s_barrier(); FENCE; } while (0)
#define VMBAR(N) do { asm volatile("s_waitcnt vmcnt(" #N ")" ::: "memory"); \
                      __builtin_amdgcn_s_barrier(); FENCE; } while (0)

__global__ __launch_bounds__(512, 2) void gemm_bt_kernel(const unsigned short* __restrict__ A,
                                                         const unsigned short* __restrict__ B,
                                                         float* __restrict__ C) {
  __shared__ unsigned short lds[65536];  // 128 KiB

  const int tid  = threadIdx.x;
  const int lane = tid & 63;
  const int wv   = tid >> 6;      // 0..7
  const int wm   = wv & 1;        // M pair (rows wm*64 and 128+wm*64)
  const int wn   = wv >> 1;       // N quad (cols wn*32 and 128+wn*32)
  const int r32  = lane & 31;
  const int kh   = lane >> 5;     // k-half of fragment

  // bijective XCD chunk swizzle: 512 blocks -> 8 XCDs x (8 rows x 8 cols) chunks
  const int bid = blockIdx.x;
  const int xcd = bid & 7;
  const int loc = bid >> 3;                    // 0..63
  const int by  = (xcd >> 1) * 8 + (loc >> 3); // 0..31
  const int bx  = (xcd & 1) * 8 + (loc & 7);   // 0..15
  const int m0  = by * BM;
  const int n0  = bx * BN;

  // ---- staging geometry: instruction i covers chunk = wv*2+i (8 rows x 8 slots);
  // lane slot (srow = lane>>3, lane&7); source k-chunk = (lane&7) ^ srow ^ (chunk&7).
  const int srow = lane >> 3;
  const int l7   = lane & 7;
  const int rowoff0 = (wv * 2 + 0) * 8 + srow;
  const int rowoff1 = (wv * 2 + 1) * 8 + srow;
  const int sc0 = (l7 ^ srow ^ ((wv * 2 + 0) & 7)) * 8;
  const int sc1 = (l7 ^ srow ^ ((wv * 2 + 1) & 7)) * 8;
  const unsigned short* pA0 = A + (size_t)(m0 + rowoff0) * IN_F + sc0;
  const unsigned short* pA1 = A + (size_t)(m0 + rowoff1) * IN_F + sc1;
  const unsigned short* pB0 = B + (size_t)(n0 + rowoff0) * IN_F + sc0;
  const unsigned short* pB1 = B + (size_t)(n0 + rowoff1) * IN_F + sc1;

#define STAGE_A(bufi, h, kcol) do { \
    __builtin_amdgcn_global_load_lds((const GLOBAL_AS unsigned int*)(pA0 + (size_t)(h) * 128 * IN_F + (kcol)), \
        (LDS_AS unsigned int*)((char*)lds + (bufi) * 32768 + (h) * 16384 + (wv * 2 + 0) * 1024), 16, 0, 0); \
    __builtin_amdgcn_global_load_lds((const GLOBAL_AS unsigned int*)(pA1 + (size_t)(h) * 128 * IN_F + (kcol)), \
        (LDS_AS unsigned int*)((char*)lds + (bufi) * 32768 + (h) * 16384 + (wv * 2 + 1) * 1024), 16, 0, 0); \
  } while (0)

#define STAGE_B(bufi, h, kcol) do { \
    __builtin_amdgcn_global_load_lds((const GLOBAL_AS unsigned int*)(pB0 + (size_t)(h) * 128 * IN_F + (kcol)), \
        (LDS_AS unsigned int*)((char*)lds + 65536 + (bufi) * 32768 + (h) * 16384 + (wv * 2 + 0) * 1024), 16, 0, 0); \
    __builtin_amdgcn_global_load_lds((const GLOBAL_AS unsigned int*)(pB1 + (size_t)(h) * 128 * IN_F + (kcol)), \
        (LDS_AS unsigned int*)((char*)lds + 65536 + (bufi) * 32768 + (h) * 16384 + (wv * 2 + 1) * 1024), 16, 0, 0); \
  } while (0)

  // ---- read geometry: precomputed byte offsets (buf/half added as imm at the read)
  const int rA = wm * 64 + r32;   // A row-in-half for sm=0 (sm adds 32)
  const int rB = wn * 32 + r32;   // B row-in-half
  int offA[2][4];
  int offB[4];
#pragma unroll
  for (int sm = 0; sm < 2; ++sm) {
    const int fh = ((sm * 4) + (r32 >> 3)) & 7;   // ((row>>3)&7); wm*8 drops mod 8
#pragma unroll
    for (int k4 = 0; k4 < 4; ++k4) {
      const int pc = (2 * k4 + kh) ^ (r32 & 7) ^ fh;
      offA[sm][k4] = (rA + sm * 32) * 128 + pc * 16;
    }
  }
  {
    const int fh = ((wn * 4) + (r32 >> 3)) & 7;
#pragma unroll
    for (int k4 = 0; k4 < 4; ++k4) {
      const int pc = (2 * k4 + kh) ^ (r32 & 7) ^ fh;
      offB[k4] = 65536 + rB * 128 + pc * 16;
    }
  }

  bf16x8 af[2][4], bfr[2][4];

#define READ_A(bufi, qm) do { \
    _Pragma("unroll") for (int sm = 0; sm < 2; ++sm) \
    _Pragma("unroll") for (int k4 = 0; k4 < 4; ++k4) \
      af[sm][k4] = *(const bf16x8*)((const char*)lds + offA[sm][k4] + (bufi) * 32768 + (qm) * 16384); \
  } while (0)

#define READ_B(bufi, qn) do { \
    _Pragma("unroll") for (int k4 = 0; k4 < 4; ++k4) \
      bfr[qn][k4] = *(const bf16x8*)((const char*)lds + offB[k4] + (bufi) * 32768 + (qn) * 16384); \
  } while (0)

#define MFMA_Q(qm, qn) do { \
    __builtin_amdgcn_s_setprio(1); \
    _Pragma("unroll") for (int sm = 0; sm < 2; ++sm) \
    _Pragma("unroll") for (int k4 = 0; k4 < 4; ++k4) \
      acc[qm][sm][qn] = __builtin_amdgcn_mfma_f32_32x32x16_bf16(af[sm][k4], bfr[qn][k4], acc[qm][sm][qn], 0, 0, 0); \
    __builtin_amdgcn_s_setprio(0); \
  } while (0)

  f32x16 acc[2][2][2];
#pragma unroll
  for (int a = 0; a < 2; ++a)
#pragma unroll
    for (int b = 0; b < 2; ++b)
#pragma unroll
      for (int c = 0; c < 2; ++c)
        acc[a][b][c] = (f32x16)(0.0f);

  // ---- prologue: tile0 -> buf0 (A0,B0,B1,A1), tile1 -> buf1 (A0,B0,B1). 14 loads.
  STAGE_A(0, 0, 0); STAGE_B(0, 0, 0); STAGE_B(0, 1, 0); STAGE_A(0, 1, 0);
  STAGE_A(1, 0, BK); STAGE_B(1, 0, BK); STAGE_B(1, 1, BK);
  VMBAR(6);  // tile0 fully landed; tile1 A0/B0/B1 in flight

#pragma unroll 1
  for (int j = 0; j < NITER; ++j) {
    const int ku = (2 * j + 1) * BK;
    const int k2 = (2 * j + 2) * BK;
    const int k3 = (2 * j + 3) * BK;
    const bool more = (j < NITER - 1);

    // P1: tile t quadrant (Alow,Bleft); stage u.A1 (buf1.A.h1 last read prev P7,
    //     two end-phase barriers ago)
    READ_A(0, 0); READ_B(0, 0);
    STAGE_A(1, 1, ku);
    MFMA_Q(0, 0); BAR();

    // P2: (Alow,Bright); stage t+2.A0 (buf0.A.h0 last read P1, barrier between)
    READ_B(0, 1);
    if (more) STAGE_A(0, 0, k2);
    MFMA_Q(0, 1); BAR();

    // P3: (Ahigh,Bleft); stage t+2.B0 (buf0.B.h0 last read P1)
    READ_A(0, 1);
    if (more) STAGE_B(0, 0, k2);
    MFMA_Q(1, 0); BAR();

    // P4: (Ahigh,Bright); stage t+2.B1 (buf0.B.h1 last read P2); wait tile u landed
    if (more) STAGE_B(0, 1, k2);
    MFMA_Q(1, 1);
    if (more) { VMBAR(6); } else { VMBAR(0); }

    // P5: tile u quadrant (Alow,Bleft); stage t+2.A1 (buf0.A.h1 last read P3)
    READ_A(1, 0); READ_B(1, 0);
    if (more) STAGE_A(0, 1, k2);
    MFMA_Q(0, 0); BAR();

    // P6: (Alow,Bright); stage t+3.A0 (buf1.A.h0 last read P5)
    READ_B(1, 1);
    if (more) STAGE_A(1, 0, k3);
    MFMA_Q(0, 1); BAR();

    // P7: (Ahigh,Bleft); stage t+3.B0 (buf1.B.h0 last read P5)
    READ_A(1, 1);
    if (more) STAGE_B(1, 0, k3);
    MFMA_Q(1, 0); BAR();

    // P8: (Ahigh,Bright); stage t+3.B1 (buf1.B.h1 last read P6); wait tile t+2 landed
    if (more) STAGE_B(1, 1, k3);
    MFMA_Q(1, 1);
    if (more) { VMBAR(6); } else { BAR(); }
  }

  // ---- epilogue: C/D layout col = lane&31, row = (reg&3)+8*(reg>>2)+4*(lane>>5)
#pragma unroll
  for (int qm = 0; qm < 2; ++qm)
#pragma unroll
    for (int sm = 0; sm < 2; ++sm)
#pragma unroll
      for (int qn = 0; qn < 2; ++qn) {
        const int ncol = n0 + qn * 128 + wn * 32 + r32;
        const int mb   = m0 + qm * 128 + wm * 64 + sm * 32 + 4 * kh;
#pragma unroll
        for (int r = 0; r < 16; ++r) {
          const int mrow = mb + (r & 3) + 8 * (r >> 2);
          C[(size_t)mrow * OUT_F + ncol] = acc[qm][sm][qn][r];
        }
      }
}

extern "C" void kernel_launch(void* const* d_in, const int* in_sizes, int n_in,
                              void* d_out, int out_size, void* d_ws, size_t ws_size,
                              hipStream_t stream) {
  const float* x       = (const float*)d_in[0];   // [4,2048,4096] f32
  const int*   ternary = (const int*)d_in[1];     // [4096,4096] int {-1,0,1}
  const float* scales  = (const float*)d_in[2];   // [131072] f32
  float* out = (float*)d_out;                     // [4,2048,4096] f32

  unsigned short* xb = (unsigned short*)d_ws;                 // 67.1 MB
  unsigned short* wb = xb + (size_t)MROWS * IN_F;             // +33.6 MB

  prep_kernel<<<CVT_BLOCKS + DQ_BLOCKS, 256, 0, stream>>>(x, xb, ternary, scales, wb);

  gemm_bt_kernel<<<(MROWS / BM) * (OUT_F / BN), 512, 0, stream>>>(xb, wb, out);
}